// Round 8
// baseline (541.217 us; speedup 1.0000x reference)
//
#include <hip/hip_runtime.h>
#include <hip/hip_bf16.h>

typedef __hip_bfloat16 bf16;
typedef unsigned short u16;
typedef unsigned int u32;
typedef __attribute__((ext_vector_type(8))) short short8;     // MFMA A/B frag (8 bf16)
typedef __attribute__((ext_vector_type(8))) unsigned short ushort8;
typedef __attribute__((ext_vector_type(4))) float f32x4;      // MFMA C/D frag

#define N_NODES 100000
#define N_EDGES 1200000
#define DIM 64
#define NG 128
#define NLAYERS 4
#define BN_EPS 1e-5f

// ---- bucket-binned CSR build params ----
#define BKT_BITS 9
#define BKT 512
#define NBKT ((N_NODES + BKT - 1) / BKT)  // 196
#define SCAT_BLK 128
#define SCAT_CH ((N_EDGES + SCAT_BLK - 1) / SCAT_BLK)  // 9375
#define CSR_CAP 8192

// ---- workspace layout (float-offset units) — round-4/7 layout ----
#define WS_GSUM   0
#define WS_GSUMSQ 64
#define WS_AB     128
#define WS_FLAG   256
#define WS_GB     320     // int[129] graph row boundaries
#define WS_WALL   512     // converted fp32 weights, 37952 floats -> ends 38464
#define OFF_WEMB  0
#define OFF_BEMB  4096
#define OFF_W1    4160
#define OFF_B1    20544
#define OFF_GAMMA 20800
#define OFF_BETA  21056
#define OFF_W2    21312
#define OFF_B2    37696
#define W_TOTAL   37952
#define WS_PACC8  38464                   // pacc: float[128*64] = 8192 (region holds 65536)
#define WS_WPK    104000                  // u16[9*4096] = 18432 floats
#define WS_CUR    204000                  // ints: bhist@0, boff@256, bcur@512, dhist@768, dhcur@1024
#define WS_ROWPTR 304128                  // int[N+1]
#define WS_CSR    404160                  // int[E]
#define WS_Z      1604160                 // bf16 [N,64]
#define WS_H      4804160                 // bf16 [N,64]
#define WS_PAIR   8004160                 // u32[E]; perm[100032] aliases after CSR build
#define WS_END    9204160
#define WS_NEED_BYTES ((size_t)WS_END * 4)

#define NBLK   ((N_NODES + 63) / 64)      // 1563 row-tile blocks (100032 padded rows)

__device__ __forceinline__ float us2f(unsigned short u) {
    return __uint_as_float(((u32)u) << 16);
}
__device__ __forceinline__ short f2bs(float f) {
    bf16 b = __float2bfloat16(f);
    u16 u; __builtin_memcpy(&u, &b, 2);
    return (short)u;
}

// dual-dtype load: p is bf16* (flag=0) or float* (flag=1)
__device__ __forceinline__ float loadf(const void* p, long i, int flag) {
    if (flag) return ((const float*)p)[i];
    u32 w = ((u32)((const u16*)p)[i]) << 16;
    return __uint_as_float(w);
}

// ---- diagnostics ----
__global__ void k_diag(u32* out, float val) {
    if (threadIdx.x == 0 && blockIdx.x == 0) {
        bf16 b = __float2bfloat16(val);
        u16 bits;
        __builtin_memcpy(&bits, &b, 2);
        u32 w = ((u32)bits << 16) | bits;
        for (int i = 0; i < 8; i++) out[i] = w;
    }
}

// ---- dtype detection ----
__global__ void k_detect(const void* x, int* flag) {
    if (threadIdx.x == 0 && blockIdx.x == 0) {
        const u16* u = (const u16*)x;
        int bad = 0;
        for (int i = 0; i < 512; i++) {
            float v = __uint_as_float(((u32)u[i]) << 16);
            if (!(fabsf(v) < 100.f)) bad++;
        }
        *flag = (bad > 16) ? 1 : 0;
    }
}

// ---- convert all weights to fp32 in ws ----
__global__ __launch_bounds__(256) void k_convert(const void* W_emb, const void* b_emb,
                                                 const void* W1, const void* b1,
                                                 const void* gamma, const void* beta,
                                                 const void* W2, const void* b2,
                                                 const int* flagp, float* dst) {
    int f = *flagp;
    for (int i = blockIdx.x * blockDim.x + threadIdx.x; i < W_TOTAL;
         i += gridDim.x * blockDim.x) {
        const void* p; int off;
        if (i < OFF_BEMB)       { p = W_emb; off = i; }
        else if (i < OFF_W1)    { p = b_emb; off = i - OFF_BEMB; }
        else if (i < OFF_B1)    { p = W1;    off = i - OFF_W1; }
        else if (i < OFF_GAMMA) { p = b1;    off = i - OFF_B1; }
        else if (i < OFF_BETA)  { p = gamma; off = i - OFF_GAMMA; }
        else if (i < OFF_W2)    { p = beta;  off = i - OFF_BETA; }
        else if (i < OFF_B2)    { p = W2;    off = i - OFF_W2; }
        else                    { p = b2;    off = i - OFF_B2; }
        dst[i] = loadf(p, off, f);
    }
}

// ---- pack 9 64x64 matrices into fragment-major bf16 ----
__global__ __launch_bounds__(256) void k_pack(const float* __restrict__ wall,
                                              u16* __restrict__ wpk) {
    int i = blockIdx.x * 256 + threadIdx.x;
    if (i >= 9 * 4096) return;
    int m = i >> 12, r = i & 4095;
    int j = r & 7, l = (r >> 3) & 63, cc = (r >> 9) & 3, kk = r >> 11;
    int d = kk * 32 + ((l >> 4) << 3) + j;
    int c = cc * 16 + (l & 15);
    int moff = (m == 0) ? OFF_WEMB
             : (m <= 4 ? OFF_W1 + (m - 1) * 4096 : OFF_W2 + (m - 5) * 4096);
    wpk[i] = (u16)f2bs(wall[moff + d * 64 + c]);
}

// ---- per-graph row boundaries ----
__global__ void k_gbounds(const int* __restrict__ batch, int* __restrict__ gb) {
    int t = threadIdx.x;
    if (t <= NG) {
        int a = 0, b = N_NODES;
        while (a < b) { int m = (a + b) >> 1; if (batch[m] < t) a = m + 1; else b = m; }
        gb[t] = a;
    }
}

// ================= bucket-binned CSR build ========

__global__ __launch_bounds__(256) void k_bhist(const int* __restrict__ ei,
                                               int* __restrict__ bhist) {
    __shared__ int hl[NBKT];
    int tid = threadIdx.x;
    for (int b = tid; b < NBKT; b += 256) hl[b] = 0;
    __syncthreads();
    for (int e = blockIdx.x * 256 + tid; e < N_EDGES; e += gridDim.x * 256)
        atomicAdd(&hl[ei[N_EDGES + e] >> BKT_BITS], 1);
    __syncthreads();
    for (int b = tid; b < NBKT; b += 256)
        if (hl[b]) atomicAdd(&bhist[b], hl[b]);
}

__global__ __launch_bounds__(256) void k_bscan(const int* __restrict__ bhist,
                                               int* __restrict__ boff,
                                               int* __restrict__ bcur) {
    __shared__ int s[256];
    int tid = threadIdx.x;
    int v = (tid < NBKT) ? bhist[tid] : 0;
    s[tid] = v;
    __syncthreads();
    for (int off = 1; off < 256; off <<= 1) {
        int t = (tid >= off) ? s[tid - off] : 0;
        __syncthreads();
        s[tid] += t;
        __syncthreads();
    }
    if (tid < NBKT) { int e = s[tid] - v; boff[tid] = e; bcur[tid] = e; }
    if (tid == 0) boff[NBKT] = s[255];
}

__global__ __launch_bounds__(256) void k_bscatter(const int* __restrict__ ei,
                                                  int* __restrict__ bcur,
                                                  u32* __restrict__ pair) {
    __shared__ int cnt[NBKT];
    int tid = threadIdx.x;
    int cbeg = blockIdx.x * SCAT_CH;
    int cend = cbeg + SCAT_CH; if (cend > N_EDGES) cend = N_EDGES;
    for (int b = tid; b < NBKT; b += 256) cnt[b] = 0;
    __syncthreads();
    for (int e = cbeg + tid; e < cend; e += 256)
        atomicAdd(&cnt[ei[N_EDGES + e] >> BKT_BITS], 1);
    __syncthreads();
    for (int b = tid; b < NBKT; b += 256) {
        int c = cnt[b];
        cnt[b] = c ? atomicAdd(&bcur[b], c) : 0;
    }
    __syncthreads();
    for (int e = cbeg + tid; e < cend; e += 256) {
        int s = ei[e];
        int d = ei[N_EDGES + e];
        int pos = atomicAdd(&cnt[d >> BKT_BITS], 1);
        pair[pos] = (u32)s | ((u32)(d & (BKT - 1)) << 17);
    }
}

__global__ __launch_bounds__(256) void k_bcsr(const u32* __restrict__ pair,
                                              const int* __restrict__ boff,
                                              int* __restrict__ rowptr,
                                              int* __restrict__ csr) {
    __shared__ int degl[BKT];
    __shared__ int offl[BKT];
    __shared__ int sc[256];
    __shared__ int csrl[CSR_CAP];
    int b = blockIdx.x, tid = threadIdx.x;
    int nbase = b << BKT_BITS;
    int nodes = N_NODES - nbase; if (nodes > BKT) nodes = BKT;
    int p0 = boff[b], p1 = boff[b + 1];
    int span = p1 - p0;
    for (int i = tid; i < BKT; i += 256) degl[i] = 0;
    __syncthreads();
    for (int p = p0 + tid; p < p1; p += 256)
        atomicAdd(&degl[pair[p] >> 17], 1);
    __syncthreads();
    int a0 = degl[2 * tid], a1 = degl[2 * tid + 1];
    sc[tid] = a0 + a1;
    __syncthreads();
    for (int off = 1; off < 256; off <<= 1) {
        int t = (tid >= off) ? sc[tid - off] : 0;
        __syncthreads();
        sc[tid] += t;
        __syncthreads();
    }
    int base = sc[tid] - (a0 + a1);
    offl[2 * tid] = base;
    offl[2 * tid + 1] = base + a0;
    __syncthreads();
    for (int i = tid; i < nodes; i += 256) rowptr[nbase + i] = p0 + offl[i];
    if (b == NBKT - 1 && tid == 0) rowptr[N_NODES] = p1;
    for (int i = tid; i < BKT; i += 256) degl[i] = offl[i];
    __syncthreads();
    if (span <= CSR_CAP) {
        for (int p = p0 + tid; p < p1; p += 256) {
            u32 pk = pair[p];
            int pos = atomicAdd(&degl[pk >> 17], 1);
            csrl[pos] = (int)(pk & 0x1FFFFu);
        }
        __syncthreads();
        for (int i = tid; i < span; i += 256) csr[p0 + i] = csrl[i];
    } else {
        for (int p = p0 + tid; p < p1; p += 256) {
            u32 pk = pair[p];
            int pos = atomicAdd(&degl[pk >> 17], 1);
            csr[p0 + pos] = (int)(pk & 0x1FFFFu);
        }
    }
}

// ====== degree-sorted row permutation (counting sort, descending degree) ======

__global__ __launch_bounds__(256) void k_deghist(const int* __restrict__ rowptr,
                                                 int* __restrict__ dhist) {
    __shared__ int hl[256];
    int tid = threadIdx.x;
    hl[tid] = 0;
    __syncthreads();
    for (int i = blockIdx.x * 256 + tid; i < N_NODES; i += gridDim.x * 256) {
        int d = rowptr[i + 1] - rowptr[i];
        int b = 255 - (d > 255 ? 255 : d);
        atomicAdd(&hl[b], 1);
    }
    __syncthreads();
    if (hl[tid]) atomicAdd(&dhist[tid], hl[tid]);
}

__global__ void k_degscan(const int* __restrict__ dhist, int* __restrict__ dhcur,
                          int* __restrict__ perm) {
    __shared__ int s[256];
    int tid = threadIdx.x;
    int v = dhist[tid];
    s[tid] = v;
    __syncthreads();
    for (int off = 1; off < 256; off <<= 1) {
        int t = (tid >= off) ? s[tid - off] : 0;
        __syncthreads();
        s[tid] += t;
        __syncthreads();
    }
    dhcur[tid] = s[tid] - v;   // exclusive
    if (tid < NBLK * 64 - N_NODES) perm[N_NODES + tid] = N_NODES;  // sentinels
}

__global__ __launch_bounds__(256) void k_degfill(const int* __restrict__ rowptr,
                                                 int* __restrict__ dhcur,
                                                 int* __restrict__ perm) {
    __shared__ int cnt[256];
    int tid = threadIdx.x;
    int chunk = (N_NODES + gridDim.x - 1) / gridDim.x;
    int beg = blockIdx.x * chunk;
    int end = beg + chunk; if (end > N_NODES) end = N_NODES;
    cnt[tid] = 0;
    __syncthreads();
    for (int i = beg + tid; i < end; i += 256) {
        int d = rowptr[i + 1] - rowptr[i];
        int b = 255 - (d > 255 ? 255 : d);
        atomicAdd(&cnt[b], 1);
    }
    __syncthreads();
    int c = cnt[tid];
    cnt[tid] = c ? atomicAdd(&dhcur[tid], c) : 0;
    __syncthreads();
    for (int i = beg + tid; i < end; i += 256) {
        int d = rowptr[i + 1] - rowptr[i];
        int b = 255 - (d > 255 ? 255 : d);
        int pos = atomicAdd(&cnt[b], 1);
        perm[pos] = i;
    }
}

// ============ MFMA tile helpers ============
__device__ __forceinline__ void store_tile(u16* cb, const f32x4* acc, bf16* out,
                                           int base, int wv, int lane) {
    int r15 = lane & 15, half = lane >> 4;
#pragma unroll
    for (int cc = 0; cc < 4; cc++) {
#pragma unroll
        for (int r = 0; r < 4; r++) {
            int trow = half * 4 + r;
            int idx = (trow * 64 + cc * 16 + r15) ^ ((trow & 7) << 3);
            cb[idx] = (u16)f2bs(acc[cc][r]);
        }
    }
#pragma unroll
    for (int p = 0; p < 2; p++) {
        int trow = lane >> 2;
        int o = (trow * 64 + (lane & 3) * 8 + p * 32) ^ ((trow & 7) << 3);
        short8 val = *(const short8*)&cb[o];
        int grow = base + (wv << 4) + trow;
        if (grow < N_NODES)
            *(short8*)((u16*)out + (long)grow * 64 + (lane & 3) * 8 + p * 32) = val;
    }
}

// permuted variant: output row ids come from the per-block perm slice in LDS
__device__ __forceinline__ void store_tile_p(u16* cb, const f32x4* acc, bf16* out,
                                             const int* pl, int wv, int lane) {
    int r15 = lane & 15, half = lane >> 4;
#pragma unroll
    for (int cc = 0; cc < 4; cc++) {
#pragma unroll
        for (int r = 0; r < 4; r++) {
            int trow = half * 4 + r;
            int idx = (trow * 64 + cc * 16 + r15) ^ ((trow & 7) << 3);
            cb[idx] = (u16)f2bs(acc[cc][r]);
        }
    }
#pragma unroll
    for (int p = 0; p < 2; p++) {
        int trow = lane >> 2;
        int o = (trow * 64 + (lane & 3) * 8 + p * 32) ^ ((trow & 7) << 3);
        short8 val = *(const short8*)&cb[o];
        int grow = pl[(wv << 4) + trow];
        if (grow < N_NODES)
            *(short8*)((u16*)out + (long)grow * 64 + (lane & 3) * 8 + p * 32) = val;
    }
}

// fused mean-pool partials: block-level LDS reduce (single-graph fast path),
// per-row global-atomic fallback for graph-boundary / tail blocks. NO threadfence.
__device__ __forceinline__ void pool_fuse(const f32x4* acc, const int* gl, float* ps,
                                          float* pacc, int wv, int lane, int tid) {
    int r15 = lane & 15, half = lane >> 4;
    if (gl[0] >= 0 && gl[0] == gl[63]) {          // whole block in one graph
#pragma unroll
        for (int cc = 0; cc < 4; cc++) {
            float s = (acc[cc][0] + acc[cc][1]) + (acc[cc][2] + acc[cc][3]);
            s += __shfl_xor(s, 16, 64);
            s += __shfl_xor(s, 32, 64);
            if (half == 0) atomicAdd(&ps[cc * 16 + r15], s);   // LDS
        }
        __syncthreads();
        if (tid < DIM) atomicAdd(&pacc[(long)gl[0] * DIM + tid], ps[tid]);
    } else {                                       // boundary/tail: per-row atomics
#pragma unroll
        for (int r = 0; r < 4; r++) {
            int g = gl[(wv << 4) + half * 4 + r];
            if (g >= 0) {
#pragma unroll
                for (int cc = 0; cc < 4; cc++)
                    atomicAdd(&pacc[(long)g * DIM + cc * 16 + r15], acc[cc][r]);
            }
        }
    }
}

// ---- embedding: h = x @ W_emb + b  (MFMA) + fused pool partials ----
__global__ __launch_bounds__(256) void k_embed(const void* __restrict__ x,
                                               const int* __restrict__ flagp,
                                               const u16* __restrict__ wpk,
                                               const float* __restrict__ bf_,
                                               bf16* __restrict__ h,
                                               const int* __restrict__ batch,
                                               float* __restrict__ pacc) {
    __shared__ u16 cbuf[4 * 1024];
    __shared__ int gl[64];
    __shared__ float ps[DIM];
    int tid = threadIdx.x, lane = tid & 63, wv = tid >> 6;
    int r15 = lane & 15, half = lane >> 4;
    int f = *flagp;
    int base = blockIdx.x * 64;
    int row = base + (wv << 4) + r15;
    bool valid = row < N_NODES;

    if (tid < 64) { int rr = base + tid; gl[tid] = (rr < N_NODES) ? batch[rr] : -1; }
    if (tid < DIM) ps[tid] = 0.f;
    __syncthreads();

    float xv[16];
#pragma unroll
    for (int j = 0; j < 16; j++) xv[j] = 0.f;
    if (valid) {
        if (f) {
            const f32x4* xp = (const f32x4*)((const float*)x + (long)row * 64 + half * 8);
            f32x4 u0 = xp[0], u1 = xp[1], w0 = xp[8], w1 = xp[9];
#pragma unroll
            for (int j = 0; j < 4; j++) {
                xv[j] = u0[j]; xv[4 + j] = u1[j];
                xv[8 + j] = w0[j]; xv[12 + j] = w1[j];
            }
        } else {
            const ushort8* xp = (const ushort8*)((const u16*)x + (long)row * 64 + half * 8);
            ushort8 s0 = xp[0], s1 = xp[4];
#pragma unroll
            for (int j = 0; j < 8; j++) { xv[j] = us2f(s0[j]); xv[8 + j] = us2f(s1[j]); }
        }
    }
    short8 A0, A1;
#pragma unroll
    for (int j = 0; j < 8; j++) { A0[j] = f2bs(xv[j]); A1[j] = f2bs(xv[8 + j]); }

    const short8* Wp = (const short8*)wpk;
    short8 Bw[8];
#pragma unroll
    for (int i = 0; i < 8; i++) Bw[i] = Wp[i * 64 + lane];
    f32x4 acc[4];
#pragma unroll
    for (int cc = 0; cc < 4; cc++) {
        float bb = bf_[cc * 16 + r15];
        acc[cc] = (f32x4){bb, bb, bb, bb};
        acc[cc] = __builtin_amdgcn_mfma_f32_16x16x32_bf16(A0, Bw[cc], acc[cc], 0, 0, 0);
        acc[cc] = __builtin_amdgcn_mfma_f32_16x16x32_bf16(A1, Bw[4 + cc], acc[cc], 0, 0, 0);
    }
    store_tile(cbuf + wv * 1024, acc, h, base, wv, lane);
    pool_fuse(acc, gl, ps, pacc, wv, lane, tid);
}

// ---- layer GEMM1, degree-permuted rows, fused depth-4 CSR gather + BN stats ----
__global__ __launch_bounds__(256) void k_layer1(const bf16* __restrict__ h,
                                                const int* __restrict__ rowptr,
                                                const int* __restrict__ csr,
                                                const int* __restrict__ perm,
                                                bf16* __restrict__ z,
                                                const u16* __restrict__ wpk,
                                                const float* __restrict__ bf_,
                                                float* __restrict__ gsum,
                                                float* __restrict__ gsumsq) {
    __shared__ u16 cbuf[4 * 1024];
    __shared__ float psum[DIM], psq[DIM];
    __shared__ int pl[64];
    int tid = threadIdx.x, lane = tid & 63, wv = tid >> 6;
    int r15 = lane & 15, half = lane >> 4;
    int base = blockIdx.x * 64;

    if (tid < DIM) { psum[tid] = 0.f; psq[tid] = 0.f; }
    if (tid < 64) pl[tid] = perm[base + tid];
    __syncthreads();

    int row = pl[(wv << 4) + r15];
    bool valid = row < N_NODES;

    float v[16];
#pragma unroll
    for (int j = 0; j < 16; j++) v[j] = 0.f;
    int p0 = 0, dg = 0;
    if (valid) {
        p0 = rowptr[row];
        dg = rowptr[row + 1] - p0;
        const ushort8* hp = (const ushort8*)((const u16*)h + (long)row * 64 + half * 8);
        ushort8 s0 = hp[0], s1 = hp[4];
#pragma unroll
        for (int j = 0; j < 8; j++) { v[j] = us2f(s0[j]); v[8 + j] = us2f(s1[j]); }
    }
    const int* cp = csr + p0;
    int t = 0;
    int n0 = 0, n1 = 0, n2 = 0, n3 = 0;
    if (4 <= dg) { n0 = cp[0]; n1 = cp[1]; n2 = cp[2]; n3 = cp[3]; }
    while (t + 4 <= dg) {
        const ushort8* q0 = (const ushort8*)((const u16*)h + (long)n0 * 64 + half * 8);
        const ushort8* q1 = (const ushort8*)((const u16*)h + (long)n1 * 64 + half * 8);
        const ushort8* q2 = (const ushort8*)((const u16*)h + (long)n2 * 64 + half * 8);
        const ushort8* q3 = (const ushort8*)((const u16*)h + (long)n3 * 64 + half * 8);
        ushort8 a0 = q0[0], b0 = q0[4];
        ushort8 a1 = q1[0], b1 = q1[4];
        ushort8 a2 = q2[0], b2 = q2[4];
        ushort8 a3 = q3[0], b3 = q3[4];
        t += 4;
        if (t + 4 <= dg) { n0 = cp[t]; n1 = cp[t + 1]; n2 = cp[t + 2]; n3 = cp[t + 3]; }
#pragma unroll
        for (int j = 0; j < 8; j++) {
            v[j]     += (us2f(a0[j]) + us2f(a1[j])) + (us2f(a2[j]) + us2f(a3[j]));
            v[8 + j] += (us2f(b0[j]) + us2f(b1[j])) + (us2f(b2[j]) + us2f(b3[j]));
        }
    }
    for (; t < dg; t++) {
        int s = cp[t];
        const ushort8* q = (const ushort8*)((const u16*)h + (long)s * 64 + half * 8);
        ushort8 a = q[0], b = q[4];
#pragma unroll
        for (int j = 0; j < 8; j++) { v[j] += us2f(a[j]); v[8 + j] += us2f(b[j]); }
    }

    short8 A0, A1;
#pragma unroll
    for (int j = 0; j < 8; j++) { A0[j] = f2bs(v[j]); A1[j] = f2bs(v[8 + j]); }

    const short8* Wp = (const short8*)wpk;
    short8 Bw[8];
#pragma unroll
    for (int i = 0; i < 8; i++) Bw[i] = Wp[i * 64 + lane];
    f32x4 acc[4];
#pragma unroll
    for (int cc = 0; cc < 4; cc++) {
        float bb = bf_[cc * 16 + r15];
        acc[cc] = (f32x4){bb, bb, bb, bb};
        acc[cc] = __builtin_amdgcn_mfma_f32_16x16x32_bf16(A0, Bw[cc], acc[cc], 0, 0, 0);
        acc[cc] = __builtin_amdgcn_mfma_f32_16x16x32_bf16(A1, Bw[4 + cc], acc[cc], 0, 0, 0);
    }

    // BN stats from fp32 accumulators (mask sentinel rows)
#pragma unroll
    for (int cc = 0; cc < 4; cc++) {
        float s = 0.f, q = 0.f;
#pragma unroll
        for (int r = 0; r < 4; r++) {
            int prow = pl[(wv << 4) + half * 4 + r];
            if (prow < N_NODES) { float val = acc[cc][r]; s += val; q += val * val; }
        }
        s += __shfl_xor(s, 16, 64); s += __shfl_xor(s, 32, 64);
        q += __shfl_xor(q, 16, 64); q += __shfl_xor(q, 32, 64);
        if (half == 0) {
            atomicAdd(&psum[cc * 16 + r15], s);
            atomicAdd(&psq[cc * 16 + r15], q);
        }
    }

    store_tile_p(cbuf + wv * 1024, acc, z, pl, wv, lane);

    __syncthreads();
    if (tid < DIM) {
        atomicAdd(&gsum[tid], psum[tid]);
        atomicAdd(&gsumsq[tid], psq[tid]);
    }
}

// fold BN into affine a*x + s
__global__ void k_stats(const float* __restrict__ gsum, const float* __restrict__ gsumsq,
                        const float* __restrict__ gamma_f, const float* __restrict__ beta_f,
                        float* __restrict__ ab) {
    int c = threadIdx.x;
    if (c < DIM) {
        float inv_n = 1.0f / (float)N_NODES;
        float mu = gsum[c] * inv_n;
        float var = fmaxf(gsumsq[c] * inv_n - mu * mu, 0.f);
        float a = gamma_f[c] * rsqrtf(var + BN_EPS);
        ab[c] = a;
        ab[DIM + c] = beta_f[c] - mu * a;
    }
}

// ---- GEMM2: h = relu(a*z+s) @ W2 + b2  (MFMA) + fused pool partials ----
__global__ __launch_bounds__(256) void k_gemm2(const bf16* __restrict__ z,
                                               bf16* __restrict__ h,
                                               const u16* __restrict__ wpk,
                                               const float* __restrict__ bf_,
                                               const float* __restrict__ ab,
                                               const int* __restrict__ batch,
                                               float* __restrict__ pacc) {
    __shared__ u16 cbuf[4 * 1024];
    __shared__ int gl[64];
    __shared__ float ps[DIM];
    int tid = threadIdx.x, lane = tid & 63, wv = tid >> 6;
    int r15 = lane & 15, half = lane >> 4;
    int base = blockIdx.x * 64;
    int row = base + (wv << 4) + r15;
    bool valid = row < N_NODES;

    if (tid < 64) { int rr = base + tid; gl[tid] = (rr < N_NODES) ? batch[rr] : -1; }
    if (tid < DIM) ps[tid] = 0.f;
    __syncthreads();

    const f32x4* ap = (const f32x4*)ab;
    f32x4 A0v = ap[half * 2], A1v = ap[half * 2 + 1];
    f32x4 A2v = ap[8 + half * 2], A3v = ap[8 + half * 2 + 1];
    f32x4 S0v = ap[16 + half * 2], S1v = ap[16 + half * 2 + 1];
    f32x4 S2v = ap[24 + half * 2], S3v = ap[24 + half * 2 + 1];

    float xv[16];
#pragma unroll
    for (int j = 0; j < 16; j++) xv[j] = 0.f;
    if (valid) {
        const ushort8* zp = (const ushort8*)((const u16*)z + (long)row * 64 + half * 8);
        ushort8 s0 = zp[0], s1 = zp[4];
#pragma unroll
        for (int j = 0; j < 4; j++) {
            xv[j]      = fmaxf(A0v[j] * us2f(s0[j])     + S0v[j], 0.f);
            xv[4 + j]  = fmaxf(A1v[j] * us2f(s0[4 + j]) + S1v[j], 0.f);
            xv[8 + j]  = fmaxf(A2v[j] * us2f(s1[j])     + S2v[j], 0.f);
            xv[12 + j] = fmaxf(A3v[j] * us2f(s1[4 + j]) + S3v[j], 0.f);
        }
    }
    short8 A0, A1;
#pragma unroll
    for (int j = 0; j < 8; j++) { A0[j] = f2bs(xv[j]); A1[j] = f2bs(xv[8 + j]); }

    const short8* Wp = (const short8*)wpk;
    short8 Bw[8];
#pragma unroll
    for (int i = 0; i < 8; i++) Bw[i] = Wp[i * 64 + lane];
    f32x4 acc[4];
#pragma unroll
    for (int cc = 0; cc < 4; cc++) {
        float bb = bf_[cc * 16 + r15];
        acc[cc] = (f32x4){bb, bb, bb, bb};
        acc[cc] = __builtin_amdgcn_mfma_f32_16x16x32_bf16(A0, Bw[cc], acc[cc], 0, 0, 0);
        acc[cc] = __builtin_amdgcn_mfma_f32_16x16x32_bf16(A1, Bw[4 + cc], acc[cc], 0, 0, 0);
    }
    store_tile(cbuf + wv * 1024, acc, h, base, wv, lane);
    pool_fuse(acc, gl, ps, pacc, wv, lane, tid);
}

// read pacc, divide by count, write output; re-zero pacc + BN stats for next rep
__global__ void k_poolw(float* __restrict__ pacc, const int* __restrict__ gb,
                        void* __restrict__ out, int rep, const int* __restrict__ flagp,
                        float* __restrict__ gsum, float* __restrict__ gsumsq) {
    int g = blockIdx.x, c = threadIdx.x;
    int f = *flagp;
    float tot = pacc[(long)g * DIM + c];
    pacc[(long)g * DIM + c] = 0.f;
    tot /= fmaxf((float)(gb[g + 1] - gb[g]), 1.f);
    long idx = (long)g * (DIM * (NLAYERS + 1)) + rep * DIM + c;
    if (f) ((float*)out)[idx] = tot;
    else   ((bf16*)out)[idx] = __float2bfloat16(tot);
    if (g == 0) { gsum[c] = 0.f; gsumsq[c] = 0.f; }
}

extern "C" void kernel_launch(void* const* d_in, const int* in_sizes, int n_in,
                              void* d_out, int out_size, void* d_ws, size_t ws_size,
                              hipStream_t stream) {
    static const int EXPECT[11] = {6400000, 2400000, 100000, 4096, 64,
                                   16384, 256, 256, 256, 16384, 256};
    int bad = (n_in == 11) ? -1 : 99;
    if (bad < 0)
        for (int i = 0; i < 11; i++)
            if (in_sizes[i] != EXPECT[i]) { bad = i; break; }
    if (bad >= 0) {
        k_diag<<<1, 64, 0, stream>>>((u32*)d_out, 3000.0f + 100.0f * (float)bad);
        return;
    }
    if (ws_size < WS_NEED_BYTES) {
        k_diag<<<1, 64, 0, stream>>>((u32*)d_out, 1000.0f + (float)(ws_size >> 20));
        return;
    }

    const void* x     = d_in[0];
    const int*  ei    = (const int*)d_in[1];
    const int*  batch = (const int*)d_in[2];

    float* ws = (float*)d_ws;
    float* gsum   = ws + WS_GSUM;
    float* gsumsq = ws + WS_GSUMSQ;
    float* ab     = ws + WS_AB;
    int*   flagp  = (int*)(ws + WS_FLAG);
    int*   gb     = (int*)(ws + WS_GB);
    float* WALL   = ws + WS_WALL;
    float* pacc   = ws + WS_PACC8;
    u16*   wpk    = (u16*)(ws + WS_WPK);
    int*   curr   = (int*)(ws + WS_CUR);
    int*   bhist  = curr;            // [196]
    int*   boff   = curr + 256;      // [197]
    int*   bcur   = curr + 512;      // [196]
    int*   dhist  = curr + 768;      // [256]
    int*   dhcur  = curr + 1024;     // [256]
    int*   rowptr = (int*)(ws + WS_ROWPTR);
    int*   csr    = (int*)(ws + WS_CSR);
    u32*   pair   = (u32*)(ws + WS_PAIR);
    int*   perm   = (int*)(ws + WS_PAIR);   // aliases pair (dead after k_bcsr)
    bf16*  z      = (bf16*)(ws + WS_Z);
    bf16*  h      = (bf16*)(ws + WS_H);

    // zero gsum/gsumsq/ab/flag/gb scratch + pacc in one shot (flag/gb rewritten below)
    hipMemsetAsync(ws, 0, (size_t)(WS_PACC8 + NG * DIM) * 4, stream);
    k_detect<<<1, 64, 0, stream>>>(x, flagp);
    k_convert<<<64, 256, 0, stream>>>(d_in[3], d_in[4], d_in[5], d_in[6],
                                      d_in[7], d_in[8], d_in[9], d_in[10], flagp, WALL);
    k_pack<<<144, 256, 0, stream>>>(WALL, wpk);
    k_gbounds<<<1, 256, 0, stream>>>(batch, gb);

    // ---- bucket-binned CSR build ----
    hipMemsetAsync(curr, 0, 1280 * sizeof(int), stream);   // bhist + dhist(+dhcur)
    k_bhist<<<256, 256, 0, stream>>>(ei, bhist);
    k_bscan<<<1, 256, 0, stream>>>(bhist, boff, bcur);
    k_bscatter<<<SCAT_BLK, 256, 0, stream>>>(ei, bcur, pair);
    k_bcsr<<<NBKT, 256, 0, stream>>>(pair, boff, rowptr, csr);

    // ---- degree-sorted row permutation (pair region is dead -> perm) ----
    k_deghist<<<128, 256, 0, stream>>>(rowptr, dhist);
    k_degscan<<<1, 256, 0, stream>>>(dhist, dhcur, perm);
    k_degfill<<<128, 256, 0, stream>>>(rowptr, dhcur, perm);

    k_embed<<<NBLK, 256, 0, stream>>>(x, flagp, wpk, WALL + OFF_BEMB, h, batch, pacc);
    k_poolw<<<NG, 64, 0, stream>>>(pacc, gb, d_out, 0, flagp, gsum, gsumsq);
    for (int l = 0; l < NLAYERS; l++) {
        k_layer1<<<NBLK, 256, 0, stream>>>(h, rowptr, csr, perm, z,
                                           wpk + (1 + l) * 4096,
                                           WALL + OFF_B1 + l * DIM, gsum, gsumsq);
        k_stats<<<1, 64, 0, stream>>>(gsum, gsumsq, WALL + OFF_GAMMA + l * DIM,
                                      WALL + OFF_BETA + l * DIM, ab);
        k_gemm2<<<NBLK, 256, 0, stream>>>(z, h, wpk + (5 + l) * 4096,
                                          WALL + OFF_B2 + l * DIM, ab, batch, pacc);
        k_poolw<<<NG, 64, 0, stream>>>(pacc, gb, d_out, l + 1, flagp, gsum, gsumsq);
    }
}

// Round 9
// 477.697 us; speedup vs baseline: 1.1330x; 1.1330x over previous
//
#include <hip/hip_runtime.h>
#include <hip/hip_bf16.h>

typedef __hip_bfloat16 bf16;
typedef unsigned short u16;
typedef unsigned int u32;
typedef __attribute__((ext_vector_type(8))) short short8;     // MFMA A/B frag (8 bf16)
typedef __attribute__((ext_vector_type(8))) unsigned short ushort8;
typedef __attribute__((ext_vector_type(4))) float f32x4;      // MFMA C/D frag

#define N_NODES 100000
#define N_EDGES 1200000
#define DIM 64
#define NG 128
#define NLAYERS 4
#define BN_EPS 1e-5f

// ---- bucket-binned CSR build params ----
#define BKT_BITS 9
#define BKT 512
#define NBKT ((N_NODES + BKT - 1) / BKT)  // 196
#define SCAT_BLK 128
#define SCAT_CH ((N_EDGES + SCAT_BLK - 1) / SCAT_BLK)  // 9375
#define CSR_CAP 8192

// ---- workspace layout (float-offset units) — round-7 layout ----
#define WS_GSUM   0
#define WS_GSUMSQ 64
#define WS_AB     128     // unused now (BN affine computed in-kernel)
#define WS_FLAG   256
#define WS_GB     320     // int[129] graph row boundaries
#define WS_WALL   512     // converted fp32 weights, 37952 floats -> ends 38464
#define OFF_WEMB  0
#define OFF_BEMB  4096
#define OFF_W1    4160
#define OFF_B1    20544
#define OFF_GAMMA 20800
#define OFF_BETA  21056
#define OFF_W2    21312
#define OFF_B2    37696
#define W_TOTAL   37952
#define WS_WPK    104000                  // u16[9*4096] = 18432 floats
#define WS_CUR    204000                  // ints: bhist@0, boff@256, bcur@512, dhist@768, dhcur@1024
#define WS_ROWPTR 304128                  // int[N+1]
#define WS_CSR    404160                  // int[E]
#define WS_Z      1604160                 // bf16 [N,64]
#define WS_H      4804160                 // bf16 [N,64]
#define WS_PAIR   8004160                 // u32[E]; perm[100032] aliases after CSR build
#define WS_END    9204160
#define WS_NEED_BYTES ((size_t)WS_END * 4)

#define NBLK   ((N_NODES + 63) / 64)      // 1563 row-tile blocks (100032 padded rows)

__device__ __forceinline__ float us2f(unsigned short u) {
    return __uint_as_float(((u32)u) << 16);
}
__device__ __forceinline__ short f2bs(float f) {
    bf16 b = __float2bfloat16(f);
    u16 u; __builtin_memcpy(&u, &b, 2);
    return (short)u;
}

// dual-dtype load: p is bf16* (flag=0) or float* (flag=1)
__device__ __forceinline__ float loadf(const void* p, long i, int flag) {
    if (flag) return ((const float*)p)[i];
    u32 w = ((u32)((const u16*)p)[i]) << 16;
    return __uint_as_float(w);
}

// ---- diagnostics ----
__global__ void k_diag(u32* out, float val) {
    if (threadIdx.x == 0 && blockIdx.x == 0) {
        bf16 b = __float2bfloat16(val);
        u16 bits;
        __builtin_memcpy(&bits, &b, 2);
        u32 w = ((u32)bits << 16) | bits;
        for (int i = 0; i < 8; i++) out[i] = w;
    }
}

// ---- dtype detection ----
__global__ void k_detect(const void* x, int* flag) {
    if (threadIdx.x == 0 && blockIdx.x == 0) {
        const u16* u = (const u16*)x;
        int bad = 0;
        for (int i = 0; i < 512; i++) {
            float v = __uint_as_float(((u32)u[i]) << 16);
            if (!(fabsf(v) < 100.f)) bad++;
        }
        *flag = (bad > 16) ? 1 : 0;
    }
}

// ---- convert all weights to fp32 in ws ----
__global__ __launch_bounds__(256) void k_convert(const void* W_emb, const void* b_emb,
                                                 const void* W1, const void* b1,
                                                 const void* gamma, const void* beta,
                                                 const void* W2, const void* b2,
                                                 const int* flagp, float* dst) {
    int f = *flagp;
    for (int i = blockIdx.x * blockDim.x + threadIdx.x; i < W_TOTAL;
         i += gridDim.x * blockDim.x) {
        const void* p; int off;
        if (i < OFF_BEMB)       { p = W_emb; off = i; }
        else if (i < OFF_W1)    { p = b_emb; off = i - OFF_BEMB; }
        else if (i < OFF_B1)    { p = W1;    off = i - OFF_W1; }
        else if (i < OFF_GAMMA) { p = b1;    off = i - OFF_B1; }
        else if (i < OFF_BETA)  { p = gamma; off = i - OFF_GAMMA; }
        else if (i < OFF_W2)    { p = beta;  off = i - OFF_BETA; }
        else if (i < OFF_B2)    { p = W2;    off = i - OFF_W2; }
        else                    { p = b2;    off = i - OFF_B2; }
        dst[i] = loadf(p, off, f);
    }
}

// ---- pack 9 64x64 matrices into fragment-major bf16 ----
__global__ __launch_bounds__(256) void k_pack(const float* __restrict__ wall,
                                              u16* __restrict__ wpk) {
    int i = blockIdx.x * 256 + threadIdx.x;
    if (i >= 9 * 4096) return;
    int m = i >> 12, r = i & 4095;
    int j = r & 7, l = (r >> 3) & 63, cc = (r >> 9) & 3, kk = r >> 11;
    int d = kk * 32 + ((l >> 4) << 3) + j;
    int c = cc * 16 + (l & 15);
    int moff = (m == 0) ? OFF_WEMB
             : (m <= 4 ? OFF_W1 + (m - 1) * 4096 : OFF_W2 + (m - 5) * 4096);
    wpk[i] = (u16)f2bs(wall[moff + d * 64 + c]);
}

// ---- per-graph row boundaries ----
__global__ void k_gbounds(const int* __restrict__ batch, int* __restrict__ gb) {
    int t = threadIdx.x;
    if (t <= NG) {
        int a = 0, b = N_NODES;
        while (a < b) { int m = (a + b) >> 1; if (batch[m] < t) a = m + 1; else b = m; }
        gb[t] = a;
    }
}

// ================= bucket-binned CSR build ========

__global__ __launch_bounds__(256) void k_bhist(const int* __restrict__ ei,
                                               int* __restrict__ bhist) {
    __shared__ int hl[NBKT];
    int tid = threadIdx.x;
    for (int b = tid; b < NBKT; b += 256) hl[b] = 0;
    __syncthreads();
    for (int e = blockIdx.x * 256 + tid; e < N_EDGES; e += gridDim.x * 256)
        atomicAdd(&hl[ei[N_EDGES + e] >> BKT_BITS], 1);
    __syncthreads();
    for (int b = tid; b < NBKT; b += 256)
        if (hl[b]) atomicAdd(&bhist[b], hl[b]);
}

__global__ __launch_bounds__(256) void k_bscan(const int* __restrict__ bhist,
                                               int* __restrict__ boff,
                                               int* __restrict__ bcur) {
    __shared__ int s[256];
    int tid = threadIdx.x;
    int v = (tid < NBKT) ? bhist[tid] : 0;
    s[tid] = v;
    __syncthreads();
    for (int off = 1; off < 256; off <<= 1) {
        int t = (tid >= off) ? s[tid - off] : 0;
        __syncthreads();
        s[tid] += t;
        __syncthreads();
    }
    if (tid < NBKT) { int e = s[tid] - v; boff[tid] = e; bcur[tid] = e; }
    if (tid == 0) boff[NBKT] = s[255];
}

__global__ __launch_bounds__(256) void k_bscatter(const int* __restrict__ ei,
                                                  int* __restrict__ bcur,
                                                  u32* __restrict__ pair) {
    __shared__ int cnt[NBKT];
    int tid = threadIdx.x;
    int cbeg = blockIdx.x * SCAT_CH;
    int cend = cbeg + SCAT_CH; if (cend > N_EDGES) cend = N_EDGES;
    for (int b = tid; b < NBKT; b += 256) cnt[b] = 0;
    __syncthreads();
    for (int e = cbeg + tid; e < cend; e += 256)
        atomicAdd(&cnt[ei[N_EDGES + e] >> BKT_BITS], 1);
    __syncthreads();
    for (int b = tid; b < NBKT; b += 256) {
        int c = cnt[b];
        cnt[b] = c ? atomicAdd(&bcur[b], c) : 0;
    }
    __syncthreads();
    for (int e = cbeg + tid; e < cend; e += 256) {
        int s = ei[e];
        int d = ei[N_EDGES + e];
        int pos = atomicAdd(&cnt[d >> BKT_BITS], 1);
        pair[pos] = (u32)s | ((u32)(d & (BKT - 1)) << 17);
    }
}

__global__ __launch_bounds__(256) void k_bcsr(const u32* __restrict__ pair,
                                              const int* __restrict__ boff,
                                              int* __restrict__ rowptr,
                                              int* __restrict__ csr) {
    __shared__ int degl[BKT];
    __shared__ int offl[BKT];
    __shared__ int sc[256];
    __shared__ int csrl[CSR_CAP];
    int b = blockIdx.x, tid = threadIdx.x;
    int nbase = b << BKT_BITS;
    int nodes = N_NODES - nbase; if (nodes > BKT) nodes = BKT;
    int p0 = boff[b], p1 = boff[b + 1];
    int span = p1 - p0;
    for (int i = tid; i < BKT; i += 256) degl[i] = 0;
    __syncthreads();
    for (int p = p0 + tid; p < p1; p += 256)
        atomicAdd(&degl[pair[p] >> 17], 1);
    __syncthreads();
    int a0 = degl[2 * tid], a1 = degl[2 * tid + 1];
    sc[tid] = a0 + a1;
    __syncthreads();
    for (int off = 1; off < 256; off <<= 1) {
        int t = (tid >= off) ? sc[tid - off] : 0;
        __syncthreads();
        sc[tid] += t;
        __syncthreads();
    }
    int base = sc[tid] - (a0 + a1);
    offl[2 * tid] = base;
    offl[2 * tid + 1] = base + a0;
    __syncthreads();
    for (int i = tid; i < nodes; i += 256) rowptr[nbase + i] = p0 + offl[i];
    if (b == NBKT - 1 && tid == 0) rowptr[N_NODES] = p1;
    for (int i = tid; i < BKT; i += 256) degl[i] = offl[i];
    __syncthreads();
    if (span <= CSR_CAP) {
        for (int p = p0 + tid; p < p1; p += 256) {
            u32 pk = pair[p];
            int pos = atomicAdd(&degl[pk >> 17], 1);
            csrl[pos] = (int)(pk & 0x1FFFFu);
        }
        __syncthreads();
        for (int i = tid; i < span; i += 256) csr[p0 + i] = csrl[i];
    } else {
        for (int p = p0 + tid; p < p1; p += 256) {
            u32 pk = pair[p];
            int pos = atomicAdd(&degl[pk >> 17], 1);
            csr[p0 + pos] = (int)(pk & 0x1FFFFu);
        }
    }
}

// ====== degree-sorted row permutation (counting sort, descending degree) ======

__global__ __launch_bounds__(256) void k_deghist(const int* __restrict__ rowptr,
                                                 int* __restrict__ dhist) {
    __shared__ int hl[256];
    int tid = threadIdx.x;
    hl[tid] = 0;
    __syncthreads();
    for (int i = blockIdx.x * 256 + tid; i < N_NODES; i += gridDim.x * 256) {
        int d = rowptr[i + 1] - rowptr[i];
        int b = 255 - (d > 255 ? 255 : d);
        atomicAdd(&hl[b], 1);
    }
    __syncthreads();
    if (hl[tid]) atomicAdd(&dhist[tid], hl[tid]);
}

__global__ void k_degscan(const int* __restrict__ dhist, int* __restrict__ dhcur,
                          int* __restrict__ perm) {
    __shared__ int s[256];
    int tid = threadIdx.x;
    int v = dhist[tid];
    s[tid] = v;
    __syncthreads();
    for (int off = 1; off < 256; off <<= 1) {
        int t = (tid >= off) ? s[tid - off] : 0;
        __syncthreads();
        s[tid] += t;
        __syncthreads();
    }
    dhcur[tid] = s[tid] - v;   // exclusive
    if (tid < NBLK * 64 - N_NODES) perm[N_NODES + tid] = N_NODES;  // sentinels
}

__global__ __launch_bounds__(256) void k_degfill(const int* __restrict__ rowptr,
                                                 int* __restrict__ dhcur,
                                                 int* __restrict__ perm) {
    __shared__ int cnt[256];
    int tid = threadIdx.x;
    int chunk = (N_NODES + gridDim.x - 1) / gridDim.x;
    int beg = blockIdx.x * chunk;
    int end = beg + chunk; if (end > N_NODES) end = N_NODES;
    cnt[tid] = 0;
    __syncthreads();
    for (int i = beg + tid; i < end; i += 256) {
        int d = rowptr[i + 1] - rowptr[i];
        int b = 255 - (d > 255 ? 255 : d);
        atomicAdd(&cnt[b], 1);
    }
    __syncthreads();
    int c = cnt[tid];
    cnt[tid] = c ? atomicAdd(&dhcur[tid], c) : 0;
    __syncthreads();
    for (int i = beg + tid; i < end; i += 256) {
        int d = rowptr[i + 1] - rowptr[i];
        int b = 255 - (d > 255 ? 255 : d);
        int pos = atomicAdd(&cnt[b], 1);
        perm[pos] = i;
    }
}

// ============ MFMA tile helpers ============
__device__ __forceinline__ void store_tile(u16* cb, const f32x4* acc, bf16* out,
                                           int base, int wv, int lane) {
    int r15 = lane & 15, half = lane >> 4;
#pragma unroll
    for (int cc = 0; cc < 4; cc++) {
#pragma unroll
        for (int r = 0; r < 4; r++) {
            int trow = half * 4 + r;
            int idx = (trow * 64 + cc * 16 + r15) ^ ((trow & 7) << 3);
            cb[idx] = (u16)f2bs(acc[cc][r]);
        }
    }
#pragma unroll
    for (int p = 0; p < 2; p++) {
        int trow = lane >> 2;
        int o = (trow * 64 + (lane & 3) * 8 + p * 32) ^ ((trow & 7) << 3);
        short8 val = *(const short8*)&cb[o];
        int grow = base + (wv << 4) + trow;
        if (grow < N_NODES)
            *(short8*)((u16*)out + (long)grow * 64 + (lane & 3) * 8 + p * 32) = val;
    }
}

// permuted variant: output row ids come from the per-block perm slice in LDS
__device__ __forceinline__ void store_tile_p(u16* cb, const f32x4* acc, bf16* out,
                                             const int* pl, int wv, int lane) {
    int r15 = lane & 15, half = lane >> 4;
#pragma unroll
    for (int cc = 0; cc < 4; cc++) {
#pragma unroll
        for (int r = 0; r < 4; r++) {
            int trow = half * 4 + r;
            int idx = (trow * 64 + cc * 16 + r15) ^ ((trow & 7) << 3);
            cb[idx] = (u16)f2bs(acc[cc][r]);
        }
    }
#pragma unroll
    for (int p = 0; p < 2; p++) {
        int trow = lane >> 2;
        int o = (trow * 64 + (lane & 3) * 8 + p * 32) ^ ((trow & 7) << 3);
        short8 val = *(const short8*)&cb[o];
        int grow = pl[(wv << 4) + trow];
        if (grow < N_NODES)
            *(short8*)((u16*)out + (long)grow * 64 + (lane & 3) * 8 + p * 32) = val;
    }
}

// ---- embedding: h = x @ W_emb + b  (MFMA) ----
__global__ __launch_bounds__(256) void k_embed(const void* __restrict__ x,
                                               const int* __restrict__ flagp,
                                               const u16* __restrict__ wpk,
                                               const float* __restrict__ bf_,
                                               bf16* __restrict__ h) {
    __shared__ u16 cbuf[4 * 1024];
    int tid = threadIdx.x, lane = tid & 63, wv = tid >> 6;
    int r15 = lane & 15, half = lane >> 4;
    int f = *flagp;
    int base = blockIdx.x * 64;
    int row = base + (wv << 4) + r15;
    bool valid = row < N_NODES;

    float xv[16];
#pragma unroll
    for (int j = 0; j < 16; j++) xv[j] = 0.f;
    if (valid) {
        if (f) {
            const f32x4* xp = (const f32x4*)((const float*)x + (long)row * 64 + half * 8);
            f32x4 u0 = xp[0], u1 = xp[1], w0 = xp[8], w1 = xp[9];
#pragma unroll
            for (int j = 0; j < 4; j++) {
                xv[j] = u0[j]; xv[4 + j] = u1[j];
                xv[8 + j] = w0[j]; xv[12 + j] = w1[j];
            }
        } else {
            const ushort8* xp = (const ushort8*)((const u16*)x + (long)row * 64 + half * 8);
            ushort8 s0 = xp[0], s1 = xp[4];
#pragma unroll
            for (int j = 0; j < 8; j++) { xv[j] = us2f(s0[j]); xv[8 + j] = us2f(s1[j]); }
        }
    }
    short8 A0, A1;
#pragma unroll
    for (int j = 0; j < 8; j++) { A0[j] = f2bs(xv[j]); A1[j] = f2bs(xv[8 + j]); }

    const short8* Wp = (const short8*)wpk;
    short8 Bw[8];
#pragma unroll
    for (int i = 0; i < 8; i++) Bw[i] = Wp[i * 64 + lane];
    f32x4 acc[4];
#pragma unroll
    for (int cc = 0; cc < 4; cc++) {
        float bb = bf_[cc * 16 + r15];
        acc[cc] = (f32x4){bb, bb, bb, bb};
        acc[cc] = __builtin_amdgcn_mfma_f32_16x16x32_bf16(A0, Bw[cc], acc[cc], 0, 0, 0);
        acc[cc] = __builtin_amdgcn_mfma_f32_16x16x32_bf16(A1, Bw[4 + cc], acc[cc], 0, 0, 0);
    }
    store_tile(cbuf + wv * 1024, acc, h, base, wv, lane);
}

// ---- layer GEMM1, degree-permuted rows, fused depth-4 CSR gather + BN stats ----
__global__ __launch_bounds__(256) void k_layer1(const bf16* __restrict__ h,
                                                const int* __restrict__ rowptr,
                                                const int* __restrict__ csr,
                                                const int* __restrict__ perm,
                                                bf16* __restrict__ z,
                                                const u16* __restrict__ wpk,
                                                const float* __restrict__ bf_,
                                                float* __restrict__ gsum,
                                                float* __restrict__ gsumsq) {
    __shared__ u16 cbuf[4 * 1024];
    __shared__ float psum[DIM], psq[DIM];
    __shared__ int pl[64];
    int tid = threadIdx.x, lane = tid & 63, wv = tid >> 6;
    int r15 = lane & 15, half = lane >> 4;
    int base = blockIdx.x * 64;

    if (tid < DIM) { psum[tid] = 0.f; psq[tid] = 0.f; }
    if (tid < 64) pl[tid] = perm[base + tid];
    __syncthreads();

    int row = pl[(wv << 4) + r15];
    bool valid = row < N_NODES;

    float v[16];
#pragma unroll
    for (int j = 0; j < 16; j++) v[j] = 0.f;
    int p0 = 0, dg = 0;
    if (valid) {
        p0 = rowptr[row];
        dg = rowptr[row + 1] - p0;
        const ushort8* hp = (const ushort8*)((const u16*)h + (long)row * 64 + half * 8);
        ushort8 s0 = hp[0], s1 = hp[4];
#pragma unroll
        for (int j = 0; j < 8; j++) { v[j] = us2f(s0[j]); v[8 + j] = us2f(s1[j]); }
    }
    const int* cp = csr + p0;
    int t = 0;
    int n0 = 0, n1 = 0, n2 = 0, n3 = 0;
    if (4 <= dg) { n0 = cp[0]; n1 = cp[1]; n2 = cp[2]; n3 = cp[3]; }
    while (t + 4 <= dg) {
        const ushort8* q0 = (const ushort8*)((const u16*)h + (long)n0 * 64 + half * 8);
        const ushort8* q1 = (const ushort8*)((const u16*)h + (long)n1 * 64 + half * 8);
        const ushort8* q2 = (const ushort8*)((const u16*)h + (long)n2 * 64 + half * 8);
        const ushort8* q3 = (const ushort8*)((const u16*)h + (long)n3 * 64 + half * 8);
        ushort8 a0 = q0[0], b0 = q0[4];
        ushort8 a1 = q1[0], b1 = q1[4];
        ushort8 a2 = q2[0], b2 = q2[4];
        ushort8 a3 = q3[0], b3 = q3[4];
        t += 4;
        if (t + 4 <= dg) { n0 = cp[t]; n1 = cp[t + 1]; n2 = cp[t + 2]; n3 = cp[t + 3]; }
#pragma unroll
        for (int j = 0; j < 8; j++) {
            v[j]     += (us2f(a0[j]) + us2f(a1[j])) + (us2f(a2[j]) + us2f(a3[j]));
            v[8 + j] += (us2f(b0[j]) + us2f(b1[j])) + (us2f(b2[j]) + us2f(b3[j]));
        }
    }
    for (; t < dg; t++) {
        int s = cp[t];
        const ushort8* q = (const ushort8*)((const u16*)h + (long)s * 64 + half * 8);
        ushort8 a = q[0], b = q[4];
#pragma unroll
        for (int j = 0; j < 8; j++) { v[j] += us2f(a[j]); v[8 + j] += us2f(b[j]); }
    }

    short8 A0, A1;
#pragma unroll
    for (int j = 0; j < 8; j++) { A0[j] = f2bs(v[j]); A1[j] = f2bs(v[8 + j]); }

    const short8* Wp = (const short8*)wpk;
    short8 Bw[8];
#pragma unroll
    for (int i = 0; i < 8; i++) Bw[i] = Wp[i * 64 + lane];
    f32x4 acc[4];
#pragma unroll
    for (int cc = 0; cc < 4; cc++) {
        float bb = bf_[cc * 16 + r15];
        acc[cc] = (f32x4){bb, bb, bb, bb};
        acc[cc] = __builtin_amdgcn_mfma_f32_16x16x32_bf16(A0, Bw[cc], acc[cc], 0, 0, 0);
        acc[cc] = __builtin_amdgcn_mfma_f32_16x16x32_bf16(A1, Bw[4 + cc], acc[cc], 0, 0, 0);
    }

    // BN stats from fp32 accumulators (mask sentinel rows)
#pragma unroll
    for (int cc = 0; cc < 4; cc++) {
        float s = 0.f, q = 0.f;
#pragma unroll
        for (int r = 0; r < 4; r++) {
            int prow = pl[(wv << 4) + half * 4 + r];
            if (prow < N_NODES) { float val = acc[cc][r]; s += val; q += val * val; }
        }
        s += __shfl_xor(s, 16, 64); s += __shfl_xor(s, 32, 64);
        q += __shfl_xor(q, 16, 64); q += __shfl_xor(q, 32, 64);
        if (half == 0) {
            atomicAdd(&psum[cc * 16 + r15], s);
            atomicAdd(&psq[cc * 16 + r15], q);
        }
    }

    store_tile_p(cbuf + wv * 1024, acc, z, pl, wv, lane);

    __syncthreads();
    if (tid < DIM) {
        atomicAdd(&gsum[tid], psum[tid]);
        atomicAdd(&gsumsq[tid], psq[tid]);
    }
}

// ---- GEMM2: h = relu(a*z+s) @ W2 + b2  (MFMA), BN affine computed in-block ----
__global__ __launch_bounds__(256) void k_gemm2(const bf16* __restrict__ z,
                                               bf16* __restrict__ h,
                                               const u16* __restrict__ wpk,
                                               const float* __restrict__ bf_,
                                               const float* __restrict__ gsum,
                                               const float* __restrict__ gsumsq,
                                               const float* __restrict__ gamma_f,
                                               const float* __restrict__ beta_f) {
    __shared__ u16 cbuf[4 * 1024];
    __shared__ float al[DIM], sl[DIM];
    int tid = threadIdx.x, lane = tid & 63, wv = tid >> 6;
    int r15 = lane & 15, half = lane >> 4;
    int base = blockIdx.x * 64;
    int row = base + (wv << 4) + r15;
    bool valid = row < N_NODES;

    if (tid < DIM) {   // fold BN into affine: identical inputs in every block
        float inv_n = 1.0f / (float)N_NODES;
        float mu = gsum[tid] * inv_n;
        float var = fmaxf(gsumsq[tid] * inv_n - mu * mu, 0.f);
        float a = gamma_f[tid] * rsqrtf(var + BN_EPS);
        al[tid] = a;
        sl[tid] = beta_f[tid] - mu * a;
    }
    __syncthreads();

    float xv[16];
#pragma unroll
    for (int j = 0; j < 16; j++) xv[j] = 0.f;
    if (valid) {
        const ushort8* zp = (const ushort8*)((const u16*)z + (long)row * 64 + half * 8);
        ushort8 s0 = zp[0], s1 = zp[4];
        int c0 = half * 8;
#pragma unroll
        for (int j = 0; j < 8; j++) {
            xv[j]     = fmaxf(al[c0 + j] * us2f(s0[j]) + sl[c0 + j], 0.f);
            xv[8 + j] = fmaxf(al[32 + c0 + j] * us2f(s1[j]) + sl[32 + c0 + j], 0.f);
        }
    }
    short8 A0, A1;
#pragma unroll
    for (int j = 0; j < 8; j++) { A0[j] = f2bs(xv[j]); A1[j] = f2bs(xv[8 + j]); }

    const short8* Wp = (const short8*)wpk;
    short8 Bw[8];
#pragma unroll
    for (int i = 0; i < 8; i++) Bw[i] = Wp[i * 64 + lane];
    f32x4 acc[4];
#pragma unroll
    for (int cc = 0; cc < 4; cc++) {
        float bb = bf_[cc * 16 + r15];
        acc[cc] = (f32x4){bb, bb, bb, bb};
        acc[cc] = __builtin_amdgcn_mfma_f32_16x16x32_bf16(A0, Bw[cc], acc[cc], 0, 0, 0);
        acc[cc] = __builtin_amdgcn_mfma_f32_16x16x32_bf16(A1, Bw[4 + cc], acc[cc], 0, 0, 0);
    }
    store_tile(cbuf + wv * 1024, acc, h, base, wv, lane);
}

// ---- merged mean-pool: reduce graph, divide, write output; block 0 zeroes BN stats
__global__ __launch_bounds__(1024) void k_pool(const bf16* __restrict__ h,
                                               const int* __restrict__ gb,
                                               void* __restrict__ out, int rep,
                                               const int* __restrict__ flagp,
                                               float* __restrict__ gstats) {
    __shared__ float ps[16][DIM];
    int g = blockIdx.x;
    int tid = threadIdx.x, lane = tid & 63, wv = tid >> 6;   // 16 waves
    int chunk = lane & 7, rg = lane >> 3;
    int lo = gb[g], hi = gb[g + 1];
    float acc[8];
#pragma unroll
    for (int j = 0; j < 8; j++) acc[j] = 0.f;
    for (int r = lo + wv * 8 + rg; r < hi; r += 128) {
        ushort8 d = *(const ushort8*)((const u16*)h + (long)r * 64 + chunk * 8);
#pragma unroll
        for (int j = 0; j < 8; j++) acc[j] += us2f(d[j]);
    }
#pragma unroll
    for (int j = 0; j < 8; j++) {
        acc[j] += __shfl_xor(acc[j], 8, 64);
        acc[j] += __shfl_xor(acc[j], 16, 64);
        acc[j] += __shfl_xor(acc[j], 32, 64);
    }
    if (rg == 0) {
#pragma unroll
        for (int j = 0; j < 8; j++) ps[wv][chunk * 8 + j] = acc[j];
    }
    __syncthreads();
    if (tid < DIM) {
        float tot = 0.f;
#pragma unroll
        for (int w = 0; w < 16; w++) tot += ps[w][tid];
        tot /= fmaxf((float)(hi - lo), 1.f);
        long idx = (long)g * (DIM * (NLAYERS + 1)) + rep * DIM + tid;
        if (*flagp) ((float*)out)[idx] = tot;
        else        ((bf16*)out)[idx] = __float2bfloat16(tot);
    }
    if (g == 0 && tid >= 128 && tid < 256) gstats[tid - 128] = 0.f;  // gsum+gsumsq
}

extern "C" void kernel_launch(void* const* d_in, const int* in_sizes, int n_in,
                              void* d_out, int out_size, void* d_ws, size_t ws_size,
                              hipStream_t stream) {
    static const int EXPECT[11] = {6400000, 2400000, 100000, 4096, 64,
                                   16384, 256, 256, 256, 16384, 256};
    int bad = (n_in == 11) ? -1 : 99;
    if (bad < 0)
        for (int i = 0; i < 11; i++)
            if (in_sizes[i] != EXPECT[i]) { bad = i; break; }
    if (bad >= 0) {
        k_diag<<<1, 64, 0, stream>>>((u32*)d_out, 3000.0f + 100.0f * (float)bad);
        return;
    }
    if (ws_size < WS_NEED_BYTES) {
        k_diag<<<1, 64, 0, stream>>>((u32*)d_out, 1000.0f + (float)(ws_size >> 20));
        return;
    }

    const void* x     = d_in[0];
    const int*  ei    = (const int*)d_in[1];
    const int*  batch = (const int*)d_in[2];

    float* ws = (float*)d_ws;
    float* gsum   = ws + WS_GSUM;
    float* gsumsq = ws + WS_GSUMSQ;
    int*   flagp  = (int*)(ws + WS_FLAG);
    int*   gb     = (int*)(ws + WS_GB);
    float* WALL   = ws + WS_WALL;
    u16*   wpk    = (u16*)(ws + WS_WPK);
    int*   curr   = (int*)(ws + WS_CUR);
    int*   bhist  = curr;            // [196]
    int*   boff   = curr + 256;      // [197]
    int*   bcur   = curr + 512;      // [196]
    int*   dhist  = curr + 768;      // [256]
    int*   dhcur  = curr + 1024;     // [256]
    int*   rowptr = (int*)(ws + WS_ROWPTR);
    int*   csr    = (int*)(ws + WS_CSR);
    u32*   pair   = (u32*)(ws + WS_PAIR);
    int*   perm   = (int*)(ws + WS_PAIR);   // aliases pair (dead after k_bcsr)
    bf16*  z      = (bf16*)(ws + WS_Z);
    bf16*  h      = (bf16*)(ws + WS_H);

    // zero gsum/gsumsq (+ab/flag/gb scratch, rewritten below)
    hipMemsetAsync(ws, 0, 512 * sizeof(float), stream);
    k_detect<<<1, 64, 0, stream>>>(x, flagp);
    k_convert<<<64, 256, 0, stream>>>(d_in[3], d_in[4], d_in[5], d_in[6],
                                      d_in[7], d_in[8], d_in[9], d_in[10], flagp, WALL);
    k_pack<<<144, 256, 0, stream>>>(WALL, wpk);
    k_gbounds<<<1, 256, 0, stream>>>(batch, gb);

    // ---- bucket-binned CSR build ----
    hipMemsetAsync(curr, 0, 1280 * sizeof(int), stream);   // bhist + dhist(+dhcur)
    k_bhist<<<256, 256, 0, stream>>>(ei, bhist);
    k_bscan<<<1, 256, 0, stream>>>(bhist, boff, bcur);
    k_bscatter<<<SCAT_BLK, 256, 0, stream>>>(ei, bcur, pair);
    k_bcsr<<<NBKT, 256, 0, stream>>>(pair, boff, rowptr, csr);

    // ---- degree-sorted row permutation (pair region is dead -> perm) ----
    k_deghist<<<128, 256, 0, stream>>>(rowptr, dhist);
    k_degscan<<<1, 256, 0, stream>>>(dhist, dhcur, perm);
    k_degfill<<<128, 256, 0, stream>>>(rowptr, dhcur, perm);

    k_embed<<<NBLK, 256, 0, stream>>>(x, flagp, wpk, WALL + OFF_BEMB, h);
    k_pool<<<NG, 1024, 0, stream>>>(h, gb, d_out, 0, flagp, gsum);
    for (int l = 0; l < NLAYERS; l++) {
        k_layer1<<<NBLK, 256, 0, stream>>>(h, rowptr, csr, perm, z,
                                           wpk + (1 + l) * 4096,
                                           WALL + OFF_B1 + l * DIM, gsum, gsumsq);
        k_gemm2<<<NBLK, 256, 0, stream>>>(z, h, wpk + (5 + l) * 4096,
                                          WALL + OFF_B2 + l * DIM, gsum, gsumsq,
                                          WALL + OFF_GAMMA + l * DIM,
                                          WALL + OFF_BETA + l * DIM);
        k_pool<<<NG, 1024, 0, stream>>>(h, gb, d_out, l + 1, flagp, gsum);
    }
}

// Round 10
// 466.838 us; speedup vs baseline: 1.1593x; 1.0233x over previous
//
#include <hip/hip_runtime.h>
#include <hip/hip_bf16.h>

typedef __hip_bfloat16 bf16;
typedef unsigned short u16;
typedef unsigned int u32;
typedef __attribute__((ext_vector_type(8))) short short8;     // MFMA A/B frag (8 bf16)
typedef __attribute__((ext_vector_type(8))) unsigned short ushort8;
typedef __attribute__((ext_vector_type(4))) float f32x4;      // MFMA C/D frag

#define N_NODES 100000
#define N_EDGES 1200000
#define DIM 64
#define NG 128
#define NLAYERS 4
#define BN_EPS 1e-5f

// ---- bucket-binned CSR build params ----
#define BKT_BITS 9
#define BKT 512
#define NBKT ((N_NODES + BKT - 1) / BKT)  // 196
#define SCAT_BLK 128
#define SCAT_CH ((N_EDGES + SCAT_BLK - 1) / SCAT_BLK)  // 9375
#define CSR_CAP 8192

// ---- workspace layout (float-offset units) — round-9 layout ----
#define WS_GSUM   0
#define WS_GSUMSQ 64
#define WS_AB     128     // unused (BN affine computed in-kernel)
#define WS_FLAG   256
#define WS_GB     320     // int[129] graph row boundaries
#define WS_WALL   512     // converted fp32 weights, 37952 floats -> ends 38464
#define OFF_WEMB  0
#define OFF_BEMB  4096
#define OFF_W1    4160
#define OFF_B1    20544
#define OFF_GAMMA 20800
#define OFF_BETA  21056
#define OFF_W2    21312
#define OFF_B2    37696
#define W_TOTAL   37952
#define WS_WPK    104000                  // u16[9*4096] = 18432 floats
#define WS_CUR    204000                  // ints: bhist@0, boff@256, bcur@512, dhist@768, dhcur@1024
#define WS_ROWPTR 304128                  // int[N+1]
#define WS_CSR    404160                  // int[E]
#define WS_Z      1604160                 // bf16 [N,64]
#define WS_H      4804160                 // bf16 [N,64]
#define WS_PAIR   8004160                 // u32[E]; perm[100032] aliases after CSR build
#define WS_END    9204160
#define WS_NEED_BYTES ((size_t)WS_END * 4)

#define NBLK   ((N_NODES + 63) / 64)      // 1563 row-tile blocks (100032 padded rows)

__device__ __forceinline__ float us2f(unsigned short u) {
    return __uint_as_float(((u32)u) << 16);
}
__device__ __forceinline__ short f2bs(float f) {
    bf16 b = __float2bfloat16(f);
    u16 u; __builtin_memcpy(&u, &b, 2);
    return (short)u;
}

// dual-dtype load: p is bf16* (flag=0) or float* (flag=1)
__device__ __forceinline__ float loadf(const void* p, long i, int flag) {
    if (flag) return ((const float*)p)[i];
    u32 w = ((u32)((const u16*)p)[i]) << 16;
    return __uint_as_float(w);
}

// ---- diagnostics ----
__global__ void k_diag(u32* out, float val) {
    if (threadIdx.x == 0 && blockIdx.x == 0) {
        bf16 b = __float2bfloat16(val);
        u16 bits;
        __builtin_memcpy(&bits, &b, 2);
        u32 w = ((u32)bits << 16) | bits;
        for (int i = 0; i < 8; i++) out[i] = w;
    }
}

// ---- dtype detection ----
__global__ void k_detect(const void* x, int* flag) {
    if (threadIdx.x == 0 && blockIdx.x == 0) {
        const u16* u = (const u16*)x;
        int bad = 0;
        for (int i = 0; i < 512; i++) {
            float v = __uint_as_float(((u32)u[i]) << 16);
            if (!(fabsf(v) < 100.f)) bad++;
        }
        *flag = (bad > 16) ? 1 : 0;
    }
}

// ---- convert all weights to fp32 in ws ----
__global__ __launch_bounds__(256) void k_convert(const void* W_emb, const void* b_emb,
                                                 const void* W1, const void* b1,
                                                 const void* gamma, const void* beta,
                                                 const void* W2, const void* b2,
                                                 const int* flagp, float* dst) {
    int f = *flagp;
    for (int i = blockIdx.x * blockDim.x + threadIdx.x; i < W_TOTAL;
         i += gridDim.x * blockDim.x) {
        const void* p; int off;
        if (i < OFF_BEMB)       { p = W_emb; off = i; }
        else if (i < OFF_W1)    { p = b_emb; off = i - OFF_BEMB; }
        else if (i < OFF_B1)    { p = W1;    off = i - OFF_W1; }
        else if (i < OFF_GAMMA) { p = b1;    off = i - OFF_B1; }
        else if (i < OFF_BETA)  { p = gamma; off = i - OFF_GAMMA; }
        else if (i < OFF_W2)    { p = beta;  off = i - OFF_BETA; }
        else if (i < OFF_B2)    { p = W2;    off = i - OFF_W2; }
        else                    { p = b2;    off = i - OFF_B2; }
        dst[i] = loadf(p, off, f);
    }
}

// ---- pack 9 64x64 matrices into fragment-major bf16 ----
__global__ __launch_bounds__(256) void k_pack(const float* __restrict__ wall,
                                              u16* __restrict__ wpk) {
    int i = blockIdx.x * 256 + threadIdx.x;
    if (i >= 9 * 4096) return;
    int m = i >> 12, r = i & 4095;
    int j = r & 7, l = (r >> 3) & 63, cc = (r >> 9) & 3, kk = r >> 11;
    int d = kk * 32 + ((l >> 4) << 3) + j;
    int c = cc * 16 + (l & 15);
    int moff = (m == 0) ? OFF_WEMB
             : (m <= 4 ? OFF_W1 + (m - 1) * 4096 : OFF_W2 + (m - 5) * 4096);
    wpk[i] = (u16)f2bs(wall[moff + d * 64 + c]);
}

// ---- per-graph row boundaries ----
__global__ void k_gbounds(const int* __restrict__ batch, int* __restrict__ gb) {
    int t = threadIdx.x;
    if (t <= NG) {
        int a = 0, b = N_NODES;
        while (a < b) { int m = (a + b) >> 1; if (batch[m] < t) a = m + 1; else b = m; }
        gb[t] = a;
    }
}

// ================= bucket-binned CSR build ========

__global__ __launch_bounds__(256) void k_bhist(const int* __restrict__ ei,
                                               int* __restrict__ bhist) {
    __shared__ int hl[NBKT];
    int tid = threadIdx.x;
    for (int b = tid; b < NBKT; b += 256) hl[b] = 0;
    __syncthreads();
    for (int e = blockIdx.x * 256 + tid; e < N_EDGES; e += gridDim.x * 256)
        atomicAdd(&hl[ei[N_EDGES + e] >> BKT_BITS], 1);
    __syncthreads();
    for (int b = tid; b < NBKT; b += 256)
        if (hl[b]) atomicAdd(&bhist[b], hl[b]);
}

__global__ __launch_bounds__(256) void k_bscan(const int* __restrict__ bhist,
                                               int* __restrict__ boff,
                                               int* __restrict__ bcur) {
    __shared__ int s[256];
    int tid = threadIdx.x;
    int v = (tid < NBKT) ? bhist[tid] : 0;
    s[tid] = v;
    __syncthreads();
    for (int off = 1; off < 256; off <<= 1) {
        int t = (tid >= off) ? s[tid - off] : 0;
        __syncthreads();
        s[tid] += t;
        __syncthreads();
    }
    if (tid < NBKT) { int e = s[tid] - v; boff[tid] = e; bcur[tid] = e; }
    if (tid == 0) boff[NBKT] = s[255];
}

__global__ __launch_bounds__(256) void k_bscatter(const int* __restrict__ ei,
                                                  int* __restrict__ bcur,
                                                  u32* __restrict__ pair) {
    __shared__ int cnt[NBKT];
    int tid = threadIdx.x;
    int cbeg = blockIdx.x * SCAT_CH;
    int cend = cbeg + SCAT_CH; if (cend > N_EDGES) cend = N_EDGES;
    for (int b = tid; b < NBKT; b += 256) cnt[b] = 0;
    __syncthreads();
    for (int e = cbeg + tid; e < cend; e += 256)
        atomicAdd(&cnt[ei[N_EDGES + e] >> BKT_BITS], 1);
    __syncthreads();
    for (int b = tid; b < NBKT; b += 256) {
        int c = cnt[b];
        cnt[b] = c ? atomicAdd(&bcur[b], c) : 0;
    }
    __syncthreads();
    for (int e = cbeg + tid; e < cend; e += 256) {
        int s = ei[e];
        int d = ei[N_EDGES + e];
        int pos = atomicAdd(&cnt[d >> BKT_BITS], 1);
        pair[pos] = (u32)s | ((u32)(d & (BKT - 1)) << 17);
    }
}

__global__ __launch_bounds__(256) void k_bcsr(const u32* __restrict__ pair,
                                              const int* __restrict__ boff,
                                              int* __restrict__ rowptr,
                                              int* __restrict__ csr) {
    __shared__ int degl[BKT];
    __shared__ int offl[BKT];
    __shared__ int sc[256];
    __shared__ int csrl[CSR_CAP];
    int b = blockIdx.x, tid = threadIdx.x;
    int nbase = b << BKT_BITS;
    int nodes = N_NODES - nbase; if (nodes > BKT) nodes = BKT;
    int p0 = boff[b], p1 = boff[b + 1];
    int span = p1 - p0;
    for (int i = tid; i < BKT; i += 256) degl[i] = 0;
    __syncthreads();
    for (int p = p0 + tid; p < p1; p += 256)
        atomicAdd(&degl[pair[p] >> 17], 1);
    __syncthreads();
    int a0 = degl[2 * tid], a1 = degl[2 * tid + 1];
    sc[tid] = a0 + a1;
    __syncthreads();
    for (int off = 1; off < 256; off <<= 1) {
        int t = (tid >= off) ? sc[tid - off] : 0;
        __syncthreads();
        sc[tid] += t;
        __syncthreads();
    }
    int base = sc[tid] - (a0 + a1);
    offl[2 * tid] = base;
    offl[2 * tid + 1] = base + a0;
    __syncthreads();
    for (int i = tid; i < nodes; i += 256) rowptr[nbase + i] = p0 + offl[i];
    if (b == NBKT - 1 && tid == 0) rowptr[N_NODES] = p1;
    for (int i = tid; i < BKT; i += 256) degl[i] = offl[i];
    __syncthreads();
    if (span <= CSR_CAP) {
        for (int p = p0 + tid; p < p1; p += 256) {
            u32 pk = pair[p];
            int pos = atomicAdd(&degl[pk >> 17], 1);
            csrl[pos] = (int)(pk & 0x1FFFFu);
        }
        __syncthreads();
        for (int i = tid; i < span; i += 256) csr[p0 + i] = csrl[i];
    } else {
        for (int p = p0 + tid; p < p1; p += 256) {
            u32 pk = pair[p];
            int pos = atomicAdd(&degl[pk >> 17], 1);
            csr[p0 + pos] = (int)(pk & 0x1FFFFu);
        }
    }
}

// ====== degree-sorted row permutation (counting sort, descending degree) ======

__global__ __launch_bounds__(256) void k_deghist(const int* __restrict__ rowptr,
                                                 int* __restrict__ dhist) {
    __shared__ int hl[256];
    int tid = threadIdx.x;
    hl[tid] = 0;
    __syncthreads();
    for (int i = blockIdx.x * 256 + tid; i < N_NODES; i += gridDim.x * 256) {
        int d = rowptr[i + 1] - rowptr[i];
        int b = 255 - (d > 255 ? 255 : d);
        atomicAdd(&hl[b], 1);
    }
    __syncthreads();
    if (hl[tid]) atomicAdd(&dhist[tid], hl[tid]);
}

__global__ void k_degscan(const int* __restrict__ dhist, int* __restrict__ dhcur,
                          int* __restrict__ perm) {
    __shared__ int s[256];
    int tid = threadIdx.x;
    int v = dhist[tid];
    s[tid] = v;
    __syncthreads();
    for (int off = 1; off < 256; off <<= 1) {
        int t = (tid >= off) ? s[tid - off] : 0;
        __syncthreads();
        s[tid] += t;
        __syncthreads();
    }
    dhcur[tid] = s[tid] - v;   // exclusive
    if (tid < NBLK * 64 - N_NODES) perm[N_NODES + tid] = N_NODES;  // sentinels
}

__global__ __launch_bounds__(256) void k_degfill(const int* __restrict__ rowptr,
                                                 int* __restrict__ dhcur,
                                                 int* __restrict__ perm) {
    __shared__ int cnt[256];
    int tid = threadIdx.x;
    int chunk = (N_NODES + gridDim.x - 1) / gridDim.x;
    int beg = blockIdx.x * chunk;
    int end = beg + chunk; if (end > N_NODES) end = N_NODES;
    cnt[tid] = 0;
    __syncthreads();
    for (int i = beg + tid; i < end; i += 256) {
        int d = rowptr[i + 1] - rowptr[i];
        int b = 255 - (d > 255 ? 255 : d);
        atomicAdd(&cnt[b], 1);
    }
    __syncthreads();
    int c = cnt[tid];
    cnt[tid] = c ? atomicAdd(&dhcur[tid], c) : 0;
    __syncthreads();
    for (int i = beg + tid; i < end; i += 256) {
        int d = rowptr[i + 1] - rowptr[i];
        int b = 255 - (d > 255 ? 255 : d);
        int pos = atomicAdd(&cnt[b], 1);
        perm[pos] = i;
    }
}

// ============ MFMA tile helpers ============
__device__ __forceinline__ void store_tile(u16* cb, const f32x4* acc, bf16* out,
                                           int base, int wv, int lane) {
    int r15 = lane & 15, half = lane >> 4;
#pragma unroll
    for (int cc = 0; cc < 4; cc++) {
#pragma unroll
        for (int r = 0; r < 4; r++) {
            int trow = half * 4 + r;
            int idx = (trow * 64 + cc * 16 + r15) ^ ((trow & 7) << 3);
            cb[idx] = (u16)f2bs(acc[cc][r]);
        }
    }
#pragma unroll
    for (int p = 0; p < 2; p++) {
        int trow = lane >> 2;
        int o = (trow * 64 + (lane & 3) * 8 + p * 32) ^ ((trow & 7) << 3);
        short8 val = *(const short8*)&cb[o];
        int grow = base + (wv << 4) + trow;
        if (grow < N_NODES)
            *(short8*)((u16*)out + (long)grow * 64 + (lane & 3) * 8 + p * 32) = val;
    }
}

// permuted variant: output row ids come from the per-block perm slice in LDS
__device__ __forceinline__ void store_tile_p(u16* cb, const f32x4* acc, bf16* out,
                                             const int* pl, int wv, int lane) {
    int r15 = lane & 15, half = lane >> 4;
#pragma unroll
    for (int cc = 0; cc < 4; cc++) {
#pragma unroll
        for (int r = 0; r < 4; r++) {
            int trow = half * 4 + r;
            int idx = (trow * 64 + cc * 16 + r15) ^ ((trow & 7) << 3);
            cb[idx] = (u16)f2bs(acc[cc][r]);
        }
    }
#pragma unroll
    for (int p = 0; p < 2; p++) {
        int trow = lane >> 2;
        int o = (trow * 64 + (lane & 3) * 8 + p * 32) ^ ((trow & 7) << 3);
        short8 val = *(const short8*)&cb[o];
        int grow = pl[(wv << 4) + trow];
        if (grow < N_NODES)
            *(short8*)((u16*)out + (long)grow * 64 + (lane & 3) * 8 + p * 32) = val;
    }
}

// ---- embedding: h = x @ W_emb + b  (MFMA) ----
__global__ __launch_bounds__(256) void k_embed(const void* __restrict__ x,
                                               const int* __restrict__ flagp,
                                               const u16* __restrict__ wpk,
                                               const float* __restrict__ bf_,
                                               bf16* __restrict__ h) {
    __shared__ u16 cbuf[4 * 1024];
    int tid = threadIdx.x, lane = tid & 63, wv = tid >> 6;
    int r15 = lane & 15, half = lane >> 4;
    int f = *flagp;
    int base = blockIdx.x * 64;
    int row = base + (wv << 4) + r15;
    bool valid = row < N_NODES;

    float xv[16];
#pragma unroll
    for (int j = 0; j < 16; j++) xv[j] = 0.f;
    if (valid) {
        if (f) {
            const f32x4* xp = (const f32x4*)((const float*)x + (long)row * 64 + half * 8);
            f32x4 u0 = xp[0], u1 = xp[1], w0 = xp[8], w1 = xp[9];
#pragma unroll
            for (int j = 0; j < 4; j++) {
                xv[j] = u0[j]; xv[4 + j] = u1[j];
                xv[8 + j] = w0[j]; xv[12 + j] = w1[j];
            }
        } else {
            const ushort8* xp = (const ushort8*)((const u16*)x + (long)row * 64 + half * 8);
            ushort8 s0 = xp[0], s1 = xp[4];
#pragma unroll
            for (int j = 0; j < 8; j++) { xv[j] = us2f(s0[j]); xv[8 + j] = us2f(s1[j]); }
        }
    }
    short8 A0, A1;
#pragma unroll
    for (int j = 0; j < 8; j++) { A0[j] = f2bs(xv[j]); A1[j] = f2bs(xv[8 + j]); }

    const short8* Wp = (const short8*)wpk;
    short8 Bw[8];
#pragma unroll
    for (int i = 0; i < 8; i++) Bw[i] = Wp[i * 64 + lane];
    f32x4 acc[4];
#pragma unroll
    for (int cc = 0; cc < 4; cc++) {
        float bb = bf_[cc * 16 + r15];
        acc[cc] = (f32x4){bb, bb, bb, bb};
        acc[cc] = __builtin_amdgcn_mfma_f32_16x16x32_bf16(A0, Bw[cc], acc[cc], 0, 0, 0);
        acc[cc] = __builtin_amdgcn_mfma_f32_16x16x32_bf16(A1, Bw[4 + cc], acc[cc], 0, 0, 0);
    }
    store_tile(cbuf + wv * 1024, acc, h, base, wv, lane);
}

// ---- layer GEMM1, degree-permuted rows, fused depth-8 CSR gather + BN stats ----
#define GLD(n, aV, bV) { const ushort8* q = (const ushort8*)(hc + (long)(n) * 64); \
                         aV = q[0]; bV = q[4]; }
#define ACC2(aa, bb) { _Pragma("unroll") \
    for (int j = 0; j < 8; j++) { v[j] += us2f(aa[j]); v[8 + j] += us2f(bb[j]); } }

__global__ __launch_bounds__(256, 4) void k_layer1(const bf16* __restrict__ h,
                                                   const int* __restrict__ rowptr,
                                                   const int* __restrict__ csr,
                                                   const int* __restrict__ perm,
                                                   bf16* __restrict__ z,
                                                   const u16* __restrict__ wpk,
                                                   const float* __restrict__ bf_,
                                                   float* __restrict__ gsum,
                                                   float* __restrict__ gsumsq) {
    __shared__ u16 cbuf[4 * 1024];
    __shared__ float psum[DIM], psq[DIM];
    __shared__ int pl[64];
    int tid = threadIdx.x, lane = tid & 63, wv = tid >> 6;
    int r15 = lane & 15, half = lane >> 4;
    int base = blockIdx.x * 64;

    if (tid < DIM) { psum[tid] = 0.f; psq[tid] = 0.f; }
    if (tid < 64) pl[tid] = perm[base + tid];
    __syncthreads();

    int row = pl[(wv << 4) + r15];
    bool valid = row < N_NODES;

    float v[16];
#pragma unroll
    for (int j = 0; j < 16; j++) v[j] = 0.f;
    int p0 = 0, dg = 0;
    if (valid) {
        p0 = rowptr[row];
        dg = rowptr[row + 1] - p0;
        const ushort8* hp = (const ushort8*)((const u16*)h + (long)row * 64 + half * 8);
        ushort8 s0 = hp[0], s1 = hp[4];
#pragma unroll
        for (int j = 0; j < 8; j++) { v[j] = us2f(s0[j]); v[8 + j] = us2f(s1[j]); }
    }
    const u16* hc = (const u16*)h + half * 8;
    const int* cp = csr + p0;
    int t = 0;
    int m[8];
#pragma unroll
    for (int i = 0; i < 8; i++) m[i] = 0;
    if (8 <= dg) {
#pragma unroll
        for (int i = 0; i < 8; i++) m[i] = cp[i];
    }
    while (t + 8 <= dg) {      // depth-8 burst: 16 loads in flight per wave
        ushort8 a0, b0, a1, b1, a2, b2, a3, b3, a4, b4, a5, b5, a6, b6, a7, b7;
        GLD(m[0], a0, b0); GLD(m[1], a1, b1); GLD(m[2], a2, b2); GLD(m[3], a3, b3);
        GLD(m[4], a4, b4); GLD(m[5], a5, b5); GLD(m[6], a6, b6); GLD(m[7], a7, b7);
        t += 8;
        if (t + 8 <= dg) {     // prefetch next burst's indices
#pragma unroll
            for (int i = 0; i < 8; i++) m[i] = cp[t + i];
        }
        ACC2(a0, b0); ACC2(a1, b1); ACC2(a2, b2); ACC2(a3, b3);
        ACC2(a4, b4); ACC2(a5, b5); ACC2(a6, b6); ACC2(a7, b7);
    }
    if (t + 4 <= dg) {
        int j0 = cp[t], j1 = cp[t + 1], j2 = cp[t + 2], j3 = cp[t + 3];
        ushort8 a0, b0, a1, b1, a2, b2, a3, b3;
        GLD(j0, a0, b0); GLD(j1, a1, b1); GLD(j2, a2, b2); GLD(j3, a3, b3);
        t += 4;
        ACC2(a0, b0); ACC2(a1, b1); ACC2(a2, b2); ACC2(a3, b3);
    }
    if (t + 2 <= dg) {
        int j0 = cp[t], j1 = cp[t + 1];
        ushort8 a0, b0, a1, b1;
        GLD(j0, a0, b0); GLD(j1, a1, b1);
        t += 2;
        ACC2(a0, b0); ACC2(a1, b1);
    }
    if (t < dg) {
        int j0 = cp[t];
        ushort8 a0, b0;
        GLD(j0, a0, b0);
        ACC2(a0, b0);
    }

    short8 A0, A1;
#pragma unroll
    for (int j = 0; j < 8; j++) { A0[j] = f2bs(v[j]); A1[j] = f2bs(v[8 + j]); }

    const short8* Wp = (const short8*)wpk;
    short8 Bw[8];
#pragma unroll
    for (int i = 0; i < 8; i++) Bw[i] = Wp[i * 64 + lane];
    f32x4 acc[4];
#pragma unroll
    for (int cc = 0; cc < 4; cc++) {
        float bb = bf_[cc * 16 + r15];
        acc[cc] = (f32x4){bb, bb, bb, bb};
        acc[cc] = __builtin_amdgcn_mfma_f32_16x16x32_bf16(A0, Bw[cc], acc[cc], 0, 0, 0);
        acc[cc] = __builtin_amdgcn_mfma_f32_16x16x32_bf16(A1, Bw[4 + cc], acc[cc], 0, 0, 0);
    }

    // BN stats from fp32 accumulators (mask sentinel rows)
#pragma unroll
    for (int cc = 0; cc < 4; cc++) {
        float s = 0.f, q = 0.f;
#pragma unroll
        for (int r = 0; r < 4; r++) {
            int prow = pl[(wv << 4) + half * 4 + r];
            if (prow < N_NODES) { float val = acc[cc][r]; s += val; q += val * val; }
        }
        s += __shfl_xor(s, 16, 64); s += __shfl_xor(s, 32, 64);
        q += __shfl_xor(q, 16, 64); q += __shfl_xor(q, 32, 64);
        if (half == 0) {
            atomicAdd(&psum[cc * 16 + r15], s);
            atomicAdd(&psq[cc * 16 + r15], q);
        }
    }

    store_tile_p(cbuf + wv * 1024, acc, z, pl, wv, lane);

    __syncthreads();
    if (tid < DIM) {
        atomicAdd(&gsum[tid], psum[tid]);
        atomicAdd(&gsumsq[tid], psq[tid]);
    }
}

// ---- GEMM2: h = relu(a*z+s) @ W2 + b2  (MFMA), BN affine computed in-block ----
__global__ __launch_bounds__(256) void k_gemm2(const bf16* __restrict__ z,
                                               bf16* __restrict__ h,
                                               const u16* __restrict__ wpk,
                                               const float* __restrict__ bf_,
                                               const float* __restrict__ gsum,
                                               const float* __restrict__ gsumsq,
                                               const float* __restrict__ gamma_f,
                                               const float* __restrict__ beta_f) {
    __shared__ u16 cbuf[4 * 1024];
    __shared__ float al[DIM], sl[DIM];
    int tid = threadIdx.x, lane = tid & 63, wv = tid >> 6;
    int r15 = lane & 15, half = lane >> 4;
    int base = blockIdx.x * 64;
    int row = base + (wv << 4) + r15;
    bool valid = row < N_NODES;

    if (tid < DIM) {   // fold BN into affine: identical inputs in every block
        float inv_n = 1.0f / (float)N_NODES;
        float mu = gsum[tid] * inv_n;
        float var = fmaxf(gsumsq[tid] * inv_n - mu * mu, 0.f);
        float a = gamma_f[tid] * rsqrtf(var + BN_EPS);
        al[tid] = a;
        sl[tid] = beta_f[tid] - mu * a;
    }
    __syncthreads();

    float xv[16];
#pragma unroll
    for (int j = 0; j < 16; j++) xv[j] = 0.f;
    if (valid) {
        const ushort8* zp = (const ushort8*)((const u16*)z + (long)row * 64 + half * 8);
        ushort8 s0 = zp[0], s1 = zp[4];
        int c0 = half * 8;
#pragma unroll
        for (int j = 0; j < 8; j++) {
            xv[j]     = fmaxf(al[c0 + j] * us2f(s0[j]) + sl[c0 + j], 0.f);
            xv[8 + j] = fmaxf(al[32 + c0 + j] * us2f(s1[j]) + sl[32 + c0 + j], 0.f);
        }
    }
    short8 A0, A1;
#pragma unroll
    for (int j = 0; j < 8; j++) { A0[j] = f2bs(xv[j]); A1[j] = f2bs(xv[8 + j]); }

    const short8* Wp = (const short8*)wpk;
    short8 Bw[8];
#pragma unroll
    for (int i = 0; i < 8; i++) Bw[i] = Wp[i * 64 + lane];
    f32x4 acc[4];
#pragma unroll
    for (int cc = 0; cc < 4; cc++) {
        float bb = bf_[cc * 16 + r15];
        acc[cc] = (f32x4){bb, bb, bb, bb};
        acc[cc] = __builtin_amdgcn_mfma_f32_16x16x32_bf16(A0, Bw[cc], acc[cc], 0, 0, 0);
        acc[cc] = __builtin_amdgcn_mfma_f32_16x16x32_bf16(A1, Bw[4 + cc], acc[cc], 0, 0, 0);
    }
    store_tile(cbuf + wv * 1024, acc, h, base, wv, lane);
}

// ---- merged mean-pool: reduce graph, divide, write output; block 0 zeroes BN stats
__global__ __launch_bounds__(1024) void k_pool(const bf16* __restrict__ h,
                                               const int* __restrict__ gb,
                                               void* __restrict__ out, int rep,
                                               const int* __restrict__ flagp,
                                               float* __restrict__ gstats) {
    __shared__ float ps[16][DIM];
    int g = blockIdx.x;
    int tid = threadIdx.x, lane = tid & 63, wv = tid >> 6;   // 16 waves
    int chunk = lane & 7, rg = lane >> 3;
    int lo = gb[g], hi = gb[g + 1];
    float acc[8];
#pragma unroll
    for (int j = 0; j < 8; j++) acc[j] = 0.f;
    for (int r = lo + wv * 8 + rg; r < hi; r += 128) {
        ushort8 d = *(const ushort8*)((const u16*)h + (long)r * 64 + chunk * 8);
#pragma unroll
        for (int j = 0; j < 8; j++) acc[j] += us2f(d[j]);
    }
#pragma unroll
    for (int j = 0; j < 8; j++) {
        acc[j] += __shfl_xor(acc[j], 8, 64);
        acc[j] += __shfl_xor(acc[j], 16, 64);
        acc[j] += __shfl_xor(acc[j], 32, 64);
    }
    if (rg == 0) {
#pragma unroll
        for (int j = 0; j < 8; j++) ps[wv][chunk * 8 + j] = acc[j];
    }
    __syncthreads();
    if (tid < DIM) {
        float tot = 0.f;
#pragma unroll
        for (int w = 0; w < 16; w++) tot += ps[w][tid];
        tot /= fmaxf((float)(hi - lo), 1.f);
        long idx = (long)g * (DIM * (NLAYERS + 1)) + rep * DIM + tid;
        if (*flagp) ((float*)out)[idx] = tot;
        else        ((bf16*)out)[idx] = __float2bfloat16(tot);
    }
    if (g == 0 && tid >= 128 && tid < 256) gstats[tid - 128] = 0.f;  // gsum+gsumsq
}

extern "C" void kernel_launch(void* const* d_in, const int* in_sizes, int n_in,
                              void* d_out, int out_size, void* d_ws, size_t ws_size,
                              hipStream_t stream) {
    static const int EXPECT[11] = {6400000, 2400000, 100000, 4096, 64,
                                   16384, 256, 256, 256, 16384, 256};
    int bad = (n_in == 11) ? -1 : 99;
    if (bad < 0)
        for (int i = 0; i < 11; i++)
            if (in_sizes[i] != EXPECT[i]) { bad = i; break; }
    if (bad >= 0) {
        k_diag<<<1, 64, 0, stream>>>((u32*)d_out, 3000.0f + 100.0f * (float)bad);
        return;
    }
    if (ws_size < WS_NEED_BYTES) {
        k_diag<<<1, 64, 0, stream>>>((u32*)d_out, 1000.0f + (float)(ws_size >> 20));
        return;
    }

    const void* x     = d_in[0];
    const int*  ei    = (const int*)d_in[1];
    const int*  batch = (const int*)d_in[2];

    float* ws = (float*)d_ws;
    float* gsum   = ws + WS_GSUM;
    float* gsumsq = ws + WS_GSUMSQ;
    int*   flagp  = (int*)(ws + WS_FLAG);
    int*   gb     = (int*)(ws + WS_GB);
    float* WALL   = ws + WS_WALL;
    u16*   wpk    = (u16*)(ws + WS_WPK);
    int*   curr   = (int*)(ws + WS_CUR);
    int*   bhist  = curr;            // [196]
    int*   boff   = curr + 256;      // [197]
    int*   bcur   = curr + 512;      // [196]
    int*   dhist  = curr + 768;      // [256]
    int*   dhcur  = curr + 1024;     // [256]
    int*   rowptr = (int*)(ws + WS_ROWPTR);
    int*   csr    = (int*)(ws + WS_CSR);
    u32*   pair   = (u32*)(ws + WS_PAIR);
    int*   perm   = (int*)(ws + WS_PAIR);   // aliases pair (dead after k_bcsr)
    bf16*  z      = (bf16*)(ws + WS_Z);
    bf16*  h      = (bf16*)(ws + WS_H);

    // zero gsum/gsumsq (+ab/flag/gb scratch, rewritten below)
    hipMemsetAsync(ws, 0, 512 * sizeof(float), stream);
    k_detect<<<1, 64, 0, stream>>>(x, flagp);
    k_convert<<<64, 256, 0, stream>>>(d_in[3], d_in[4], d_in[5], d_in[6],
                                      d_in[7], d_in[8], d_in[9], d_in[10], flagp, WALL);
    k_pack<<<144, 256, 0, stream>>>(WALL, wpk);
    k_gbounds<<<1, 256, 0, stream>>>(batch, gb);

    // ---- bucket-binned CSR build ----
    hipMemsetAsync(curr, 0, 1280 * sizeof(int), stream);   // bhist + dhist(+dhcur)
    k_bhist<<<256, 256, 0, stream>>>(ei, bhist);
    k_bscan<<<1, 256, 0, stream>>>(bhist, boff, bcur);
    k_bscatter<<<SCAT_BLK, 256, 0, stream>>>(ei, bcur, pair);
    k_bcsr<<<NBKT, 256, 0, stream>>>(pair, boff, rowptr, csr);

    // ---- degree-sorted row permutation (pair region is dead -> perm) ----
    k_deghist<<<128, 256, 0, stream>>>(rowptr, dhist);
    k_degscan<<<1, 256, 0, stream>>>(dhist, dhcur, perm);
    k_degfill<<<128, 256, 0, stream>>>(rowptr, dhcur, perm);

    k_embed<<<NBLK, 256, 0, stream>>>(x, flagp, wpk, WALL + OFF_BEMB, h);
    k_pool<<<NG, 1024, 0, stream>>>(h, gb, d_out, 0, flagp, gsum);
    for (int l = 0; l < NLAYERS; l++) {
        k_layer1<<<NBLK, 256, 0, stream>>>(h, rowptr, csr, perm, z,
                                           wpk + (1 + l) * 4096,
                                           WALL + OFF_B1 + l * DIM, gsum, gsumsq);
        k_gemm2<<<NBLK, 256, 0, stream>>>(z, h, wpk + (5 + l) * 4096,
                                          WALL + OFF_B2 + l * DIM, gsum, gsumsq,
                                          WALL + OFF_GAMMA + l * DIM,
                                          WALL + OFF_BETA + l * DIM);
        k_pool<<<NG, 1024, 0, stream>>>(h, gb, d_out, l + 1, flagp, gsum);
    }
}